// Round 2
// baseline (1485.639 us; speedup 1.0000x reference)
//
#include <hip/hip_runtime.h>

#define T_STEPS 1460
#define G_CELLS 5000
#define NPARAM 20
#define UH_L 15
#define NZ 1e-5f
#define KT 16

__device__ __forceinline__ float sigmoidf(float x) {
    return 1.0f / (1.0f + __expf(-x));
}

// fast pow for x>0: x^y = exp2(y*log2(x)) using raw gfx950 transcendentals
__device__ __forceinline__ float fast_pow(float x, float y) {
    return __builtin_amdgcn_exp2f(y * __builtin_amdgcn_logf(x));
}

// ---------------- gamma unit-hydrograph weights, stored [l][G] ----------------
__global__ void uh_kernel(const float* __restrict__ params,
                          float* __restrict__ uh1T, float* __restrict__ uh2T) {
    int g = blockIdx.x * blockDim.x + threadIdx.x;
    if (g >= G_CELLS) return;
    const float* pr = params + ((size_t)(T_STEPS - 1) * G_CELLS + g) * NPARAM;
    float a1 = 0.3f  + sigmoidf(pr[16]) * (20.0f - 0.3f);
    float b1 = 0.01f + sigmoidf(pr[17]) * (5.0f  - 0.01f);
    float a2 = 0.5f  + sigmoidf(pr[18]) * (13.0f - 0.5f);
    float b2 = 0.15f + sigmoidf(pr[19]) * (1.5f  - 0.15f);
    float w1[UH_L], w2[UH_L];
    float s1 = 0.f, s2 = 0.f;
    #pragma unroll
    for (int l = 0; l < UH_L; ++l) {
        float t = (float)l + 0.5f;
        w1[l] = powf(t, a1 - 1.0f) * expf(-t / b1);
        w2[l] = powf(t, a2 - 1.0f) * expf(-t / b2);
        s1 += w1[l]; s2 += w2[l];
    }
    float r1 = 1.0f / s1, r2 = 1.0f / s2;
    #pragma unroll
    for (int l = 0; l < UH_L; ++l) {
        uh1T[l * G_CELLS + g] = w1[l] * r1;
        uh2T[l * G_CELLS + g] = w2[l] * r2;
    }
}

// ---------------- sequential state recurrence: one thread per grid cell ------
__global__ void __launch_bounds__(64) rec_kernel(
        const float* __restrict__ x_phy, const float* __restrict__ params,
        float2* __restrict__ q2, float* __restrict__ qgw) {
    int g = blockIdx.x * 64 + threadIdx.x;
    if (g >= G_CELLS) return;

    const float* pr = params + ((size_t)(T_STEPS - 1) * G_CELLS + g) * NPARAM;
    float p[16];
    #pragma unroll
    for (int i = 0; i < 16; ++i) p[i] = sigmoidf(pr[i]);

    const float ddf_min    = p[0] * 20.f;
    const float ddf_plus   = p[1] * 20.f;
    const float Tbm        = -2.f + p[2] * 5.f;
    const float Kcum       = 0.01f + p[3] * 0.19f;
    const float fcmin      = p[4] * 0.1f;
    const float fcmin_plus = 0.01f + p[5] * 0.24f;
    const float Ccum       = 0.005f + p[6] * 0.045f;
    const float Tbf        = -5.f + p[7] * 7.f;
    const float Kf         = p[8] * 5.f;
    const float exp_fe     = p[9];
    const float ET_eff     = p[10] * 3.f;
    const float cr         = p[11];
    const float cvp        = 1e-5f + p[12] * (0.02f - 1e-5f);
    const float cv         = p[13] * 0.1f;
    const float cp         = 1e-5f + p[14] * (0.01f - 1e-5f);
    const float Vmax       = 0.001f + p[15] * (500.f - 0.001f);

    const float invVmax = 1.0f / Vmax;
    const float ddf_sum = ddf_min + ddf_plus;
    const float dmK     = ddf_min * Kcum;
    const float fc_sum  = fcmin + fcmin_plus;
    const float fcC     = fc_sum * Ccum;

    float S = NZ, W = NZ, C = NZ, V = 0.5f * Vmax, P = NZ;

    const int STR = G_CELLS * 3;
    const float* pl = x_phy + (size_t)g * 3;
    // depth-4 software prefetch ring (1 wave/SIMD: nothing else hides latency)
    float bp[4], bt[4], be[4];
    #pragma unroll
    for (int j = 0; j < 4; ++j) { bp[j] = pl[0]; bt[j] = pl[1]; be[j] = pl[2]; pl += STR; }

    float2* o2 = q2 + g;
    float*  og = qgw + g;

    for (int t4 = 0; t4 < T_STEPS; t4 += 4) {
        const bool pf = (t4 + 8 <= T_STEPS);   // uniform: last chunk skips prefetch
        #pragma unroll
        for (int jj = 0; jj < 4; ++jj) {
            float Pp = bp[jj], Tt = bt[jj], PE = be[jj];
            if (pf) { bp[jj] = pl[0]; bt[jj] = pl[1]; be[jj] = pl[2]; pl += STR; }

            float rain = (Tt >= 0.f) ? Pp : 0.f;
            float snow = Pp - rain;
            float xb   = fmaxf(Tbf - Tt, NZ);
            float pot_fr = Kf * fast_pow(xb, exp_fe);
            float fr   = fminf(pot_fr, W);
            W -= fr; S += fr;
            float ddf  = fminf(ddf_sum, fmaf(dmK, C, ddf_min));
            float Ssn  = S + snow;
            float melt = fminf(fmaxf(ddf * (Tt - Tbm), 0.f), Ssn);
            S = Ssn - melt;
            C = (S > NZ) ? (C + melt) : 0.f;
            float wrf  = fmaxf(fmaf(-fcC, C, fc_sum), fcmin);
            float wr   = wrf * S;
            float wtmp = W + melt + rain;
            float wa   = fmaxf(wtmp - wr, 0.f);
            W = (wa > 0.f) ? wr : wtmp;
            float RET   = ET_eff * PE;
            float ratio = V * invVmax;
            float crr   = cr * ratio;
            float ht0   = crr * wa;
            float infil = fmaxf(wa - ht0 - RET, 0.f);
            float ht1   = crr * ratio * infil;
            float ht2   = cv * V;
            float v2p   = cvp * V;
            V = V + infil - ht1 - ht2 - v2p;
            float over  = fmaxf(V - Vmax, 0.f);
            V -= over; ht1 += over;
            P += v2p;
            float ht3 = cp * P;
            P -= ht3;

            o2[0] = make_float2(ht0, ht1);
            og[0] = ht2 + ht3;
            o2 += G_CELLS; og += G_CELLS;
        }
    }
}

// ---------------- FIR (15-tap causal) + groundwater combine -------------------
__global__ void __launch_bounds__(256) fir_kernel(
        const float2* __restrict__ q2, const float* __restrict__ qgw,
        const float* __restrict__ uh1T, const float* __restrict__ uh2T,
        float* __restrict__ out) {
    int g = blockIdx.x * 256 + threadIdx.x;
    if (g >= G_CELLS) return;
    int t0 = blockIdx.y * KT;

    float w1[UH_L], w2[UH_L];
    #pragma unroll
    for (int l = 0; l < UH_L; ++l) {
        w1[l] = uh1T[l * G_CELLS + g];
        w2[l] = uh2T[l * G_CELLS + g];
    }
    // sliding window: s[k] holds q at time (t - (UH_L-1) + k)
    float s0[UH_L], s1[UH_L];
    #pragma unroll
    for (int k = 0; k < UH_L - 1; ++k) {
        int tq = t0 - (UH_L - 1) + k;
        if (tq >= 0) {
            float2 v = q2[(size_t)tq * G_CELLS + g];
            s0[k] = v.x; s1[k] = v.y;
        } else { s0[k] = 0.f; s1[k] = 0.f; }
    }
    #pragma unroll
    for (int j = 0; j < KT; ++j) {
        int t = t0 + j;
        if (t < T_STEPS) {              // uniform within block
            float2 v = q2[(size_t)t * G_CELLS + g];
            s0[UH_L - 1] = v.x; s1[UH_L - 1] = v.y;
            float acc = qgw[(size_t)t * G_CELLS + g];
            #pragma unroll
            for (int l = 0; l < UH_L; ++l)
                acc += s0[UH_L - 1 - l] * w1[l] + s1[UH_L - 1 - l] * w2[l];
            out[(size_t)t * G_CELLS + g] = acc;
            #pragma unroll
            for (int k = 0; k < UH_L - 1; ++k) { s0[k] = s0[k + 1]; s1[k] = s1[k + 1]; }
        }
    }
}

extern "C" void kernel_launch(void* const* d_in, const int* in_sizes, int n_in,
                              void* d_out, int out_size, void* d_ws, size_t ws_size,
                              hipStream_t stream) {
    const float* x_phy  = (const float*)d_in[0];   // (T, G, 3) f32
    const float* params = (const float*)d_in[1];   // (T, G, 20) f32
    float* out = (float*)d_out;                    // (T, G) f32

    char* ws = (char*)d_ws;
    float2* q2   = (float2*)ws;                                        // T*G*8 B
    float*  qgw  = (float*)(ws + (size_t)T_STEPS * G_CELLS * 8);       // T*G*4 B
    float*  uh1T = (float*)(ws + (size_t)T_STEPS * G_CELLS * 12);      // 15*G*4 B
    float*  uh2T = uh1T + UH_L * G_CELLS;                              // 15*G*4 B

    uh_kernel<<<(G_CELLS + 255) / 256, 256, 0, stream>>>(params, uh1T, uh2T);
    rec_kernel<<<(G_CELLS + 63) / 64, 64, 0, stream>>>(x_phy, params, q2, qgw);
    dim3 fgrid((G_CELLS + 255) / 256, (T_STEPS + KT - 1) / KT);
    fir_kernel<<<fgrid, 256, 0, stream>>>(q2, qgw, uh1T, uh2T, out);
}

// Round 3
// 934.014 us; speedup vs baseline: 1.5906x; 1.5906x over previous
//
#include <hip/hip_runtime.h>

#define T_STEPS 1460
#define G_CELLS 5000
#define NPARAM 20
#define UH_L 15
#define NZ 1e-5f
#define KT 16
#define DCH 10                      // rec chunk depth (T_STEPS % DCH == 0)
#define NCH (T_STEPS / DCH)         // 146 chunks (even)

__device__ __forceinline__ float sigmoidf(float x) {
    return 1.0f / (1.0f + __expf(-x));
}

// fast pow for x>0: x^y = exp2(y*log2(x)) using raw gfx950 transcendentals
__device__ __forceinline__ float fast_pow(float x, float y) {
    return __builtin_amdgcn_exp2f(y * __builtin_amdgcn_logf(x));
}

// ---------------- gamma unit-hydrograph weights, stored [l][G] ----------------
__global__ void uh_kernel(const float* __restrict__ params,
                          float* __restrict__ uh1T, float* __restrict__ uh2T) {
    int g = blockIdx.x * blockDim.x + threadIdx.x;
    if (g >= G_CELLS) return;
    const float* pr = params + ((size_t)(T_STEPS - 1) * G_CELLS + g) * NPARAM;
    float a1 = 0.3f  + sigmoidf(pr[16]) * (20.0f - 0.3f);
    float b1 = 0.01f + sigmoidf(pr[17]) * (5.0f  - 0.01f);
    float a2 = 0.5f  + sigmoidf(pr[18]) * (13.0f - 0.5f);
    float b2 = 0.15f + sigmoidf(pr[19]) * (1.5f  - 0.15f);
    float w1[UH_L], w2[UH_L];
    float s1 = 0.f, s2 = 0.f;
    #pragma unroll
    for (int l = 0; l < UH_L; ++l) {
        float t = (float)l + 0.5f;
        w1[l] = fast_pow(t, a1 - 1.0f) * __expf(-t / b1);
        w2[l] = fast_pow(t, a2 - 1.0f) * __expf(-t / b2);
        s1 += w1[l]; s2 += w2[l];
    }
    float r1 = 1.0f / s1, r2 = 1.0f / s2;
    #pragma unroll
    for (int l = 0; l < UH_L; ++l) {
        uh1T[l * G_CELLS + g] = w1[l] * r1;
        uh2T[l * G_CELLS + g] = w2[l] * r2;
    }
}

// ---------------- sequential state recurrence: one thread per grid cell ------
// Chunked double-buffered prefetch: loads for chunk c+1 are issued as a batch
// and overlap the full compute of chunk c (~1400 cy > ~900 cy HBM latency).
__global__ void __launch_bounds__(64, 1) rec_kernel(
        const float* __restrict__ x_phy, const float* __restrict__ params,
        float2* __restrict__ q2, float* __restrict__ qgw) {
    int g = blockIdx.x * 64 + threadIdx.x;
    if (g >= G_CELLS) return;

    const float* pr = params + ((size_t)(T_STEPS - 1) * G_CELLS + g) * NPARAM;
    float p[16];
    #pragma unroll
    for (int i = 0; i < 16; ++i) p[i] = sigmoidf(pr[i]);

    const float ddf_min    = p[0] * 20.f;
    const float ddf_plus   = p[1] * 20.f;
    const float Tbm        = -2.f + p[2] * 5.f;
    const float Kcum       = 0.01f + p[3] * 0.19f;
    const float fcmin      = p[4] * 0.1f;
    const float fcmin_plus = 0.01f + p[5] * 0.24f;
    const float Ccum       = 0.005f + p[6] * 0.045f;
    const float Tbf        = -5.f + p[7] * 7.f;
    const float Kf         = p[8] * 5.f;
    const float exp_fe     = p[9];
    const float ET_eff     = p[10] * 3.f;
    const float cr         = p[11];
    const float cvp        = 1e-5f + p[12] * (0.02f - 1e-5f);
    const float cv         = p[13] * 0.1f;
    const float cp         = 1e-5f + p[14] * (0.01f - 1e-5f);
    const float Vmax       = 0.001f + p[15] * (500.f - 0.001f);

    const float invVmax = 1.0f / Vmax;
    const float ddf_sum = ddf_min + ddf_plus;
    const float dmK     = ddf_min * Kcum;
    const float fc_sum  = fcmin + fcmin_plus;
    const float fcC     = fc_sum * Ccum;

    float S = NZ, W = NZ, C = NZ, V = 0.5f * Vmax, P = NZ;

    const int STR = G_CELLS * 3;
    const float* base = x_phy + (size_t)g * 3;

    float A[DCH][3], B[DCH][3];

    auto LOAD = [&](float (&buf)[DCH][3], int c) {
        const float* pp = base + (size_t)c * DCH * STR;
        #pragma unroll
        for (int j = 0; j < DCH; ++j) {
            buf[j][0] = pp[0]; buf[j][1] = pp[1]; buf[j][2] = pp[2];
            pp += STR;
        }
    };

    auto COMPUTE = [&](float (&buf)[DCH][3], int c) {
        float ob[DCH][3];
        #pragma unroll
        for (int j = 0; j < DCH; ++j) {
            float Pp = buf[j][0], Tt = buf[j][1], PE = buf[j][2];

            float rain = (Tt >= 0.f) ? Pp : 0.f;
            float snow = Pp - rain;
            float xb   = fmaxf(Tbf - Tt, NZ);
            float pot_fr = Kf * fast_pow(xb, exp_fe);
            float fr   = fminf(pot_fr, W);
            W -= fr; S += fr;
            float ddf  = fminf(ddf_sum, fmaf(dmK, C, ddf_min));
            float Ssn  = S + snow;
            float melt = fminf(fmaxf(ddf * (Tt - Tbm), 0.f), Ssn);
            S = Ssn - melt;
            C = (S > NZ) ? (C + melt) : 0.f;
            float wrf  = fmaxf(fmaf(-fcC, C, fc_sum), fcmin);
            float wr   = wrf * S;
            float wtmp = W + melt + rain;
            float wa   = fmaxf(wtmp - wr, 0.f);
            W = (wa > 0.f) ? wr : wtmp;
            float RET   = ET_eff * PE;
            float ratio = V * invVmax;
            float crr   = cr * ratio;
            float ht0   = crr * wa;
            float infil = fmaxf(wa - ht0 - RET, 0.f);
            float ht1   = crr * ratio * infil;
            float ht2   = cv * V;
            float v2p   = cvp * V;
            V = V + infil - ht1 - ht2 - v2p;
            float over  = fmaxf(V - Vmax, 0.f);
            V -= over; ht1 += over;
            P += v2p;
            float ht3 = cp * P;
            P -= ht3;

            ob[j][0] = ht0; ob[j][1] = ht1; ob[j][2] = ht2 + ht3;
        }
        size_t t0 = (size_t)c * DCH;
        #pragma unroll
        for (int j = 0; j < DCH; ++j) {
            q2 [(t0 + j) * G_CELLS + g] = make_float2(ob[j][0], ob[j][1]);
            qgw[(t0 + j) * G_CELLS + g] = ob[j][2];
        }
    };

    LOAD(A, 0);
    for (int c = 0; c < NCH; c += 2) {
        LOAD(B, c + 1);              // c+1 < NCH always (NCH even)
        COMPUTE(A, c);
        if (c + 2 < NCH) LOAD(A, c + 2);
        COMPUTE(B, c + 1);
    }
}

// ---------------- FIR (15-tap causal) + groundwater combine -------------------
// Mod-15 ring with compile-time indices: no register shifting, no spill.
__global__ void __launch_bounds__(256) fir_kernel(
        const float2* __restrict__ q2, const float* __restrict__ qgw,
        const float* __restrict__ uh1T, const float* __restrict__ uh2T,
        float* __restrict__ out) {
    int g = blockIdx.x * 256 + threadIdx.x;
    if (g >= G_CELLS) return;
    int t0 = blockIdx.y * KT;

    float w1[UH_L], w2[UH_L];
    #pragma unroll
    for (int l = 0; l < UH_L; ++l) {
        w1[l] = uh1T[l * G_CELLS + g];
        w2[l] = uh2T[l * G_CELLS + g];
    }
    // ring slot for time tau = (tau - t0 + 14) mod 15 — compile-time after unroll
    float r0[UH_L], r1[UH_L];
    #pragma unroll
    for (int k = 0; k < UH_L - 1; ++k) {      // preload tau = t0-14+k  -> slot k
        int tq = t0 - (UH_L - 1) + k;
        if (tq >= 0) {
            float2 v = q2[(size_t)tq * G_CELLS + g];
            r0[k] = v.x; r1[k] = v.y;
        } else { r0[k] = 0.f; r1[k] = 0.f; }
    }
    #pragma unroll
    for (int j = 0; j < KT; ++j) {
        int t = t0 + j;
        if (t < T_STEPS) {                    // uniform within block
            const int ns = (j + UH_L - 1) % UH_L;   // slot for the new sample
            float2 v = q2[(size_t)t * G_CELLS + g];
            r0[ns] = v.x; r1[ns] = v.y;
            float acc = qgw[(size_t)t * G_CELLS + g];
            #pragma unroll
            for (int l = 0; l < UH_L; ++l) {
                const int idx = (j - l + UH_L - 1) % UH_L;   // slot of tau = t-l
                acc += r0[idx] * w1[l] + r1[idx] * w2[l];
            }
            out[(size_t)t * G_CELLS + g] = acc;
        }
    }
}

extern "C" void kernel_launch(void* const* d_in, const int* in_sizes, int n_in,
                              void* d_out, int out_size, void* d_ws, size_t ws_size,
                              hipStream_t stream) {
    const float* x_phy  = (const float*)d_in[0];   // (T, G, 3) f32
    const float* params = (const float*)d_in[1];   // (T, G, 20) f32
    float* out = (float*)d_out;                    // (T, G) f32

    char* ws = (char*)d_ws;
    float2* q2   = (float2*)ws;                                        // T*G*8 B
    float*  qgw  = (float*)(ws + (size_t)T_STEPS * G_CELLS * 8);       // T*G*4 B
    float*  uh1T = (float*)(ws + (size_t)T_STEPS * G_CELLS * 12);      // 15*G*4 B
    float*  uh2T = uh1T + UH_L * G_CELLS;                              // 15*G*4 B

    uh_kernel<<<(G_CELLS + 255) / 256, 256, 0, stream>>>(params, uh1T, uh2T);
    rec_kernel<<<(G_CELLS + 63) / 64, 64, 0, stream>>>(x_phy, params, q2, qgw);
    dim3 fgrid((G_CELLS + 255) / 256, (T_STEPS + KT - 1) / KT);
    fir_kernel<<<fgrid, 256, 0, stream>>>(q2, qgw, uh1T, uh2T, out);
}